// Round 1
// baseline (1203.869 us; speedup 1.0000x reference)
//
#include <hip/hip_runtime.h>
#include <cstdint>

#define B__ 16
#define S__ 512
#define NH__ 12
#define HS__ 64
#define H__ 768
#define BH__ 192            // B*NH
#define M__ 8192            // B*S
#define K__ 768
#define N3__ 2304           // 3*H
#define PLANE__ 6291456     // M*K
#define QKV_ELEMS__ 6291456 // BH*S*HS

typedef int    int4v   __attribute__((ext_vector_type(4)));
typedef short  short8  __attribute__((ext_vector_type(8)));
typedef float  float4v __attribute__((ext_vector_type(4)));

__device__ __forceinline__ unsigned short f2bf(float f) {
    unsigned u = __float_as_uint(f);
    u += 0x7fffu + ((u >> 16) & 1u);   // RNE
    return (unsigned short)(u >> 16);
}

// ---------------------------------------------------------------------------
// Kernel 1: per-row scale s_i = mean(|W_i|) in fp64, and sign bytes of W.
// rows 0..767 = Wq, 768..1535 = Wk, 1536..2303 = Wv. One wave per row.
// ---------------------------------------------------------------------------
__global__ __launch_bounds__(256)
void prep_w_kernel(const float* __restrict__ Wq, const float* __restrict__ Wk,
                   const float* __restrict__ Wv,
                   double* __restrict__ scales, signed char* __restrict__ sgnW) {
    int wid = threadIdx.x >> 6, lane = threadIdx.x & 63;
    int row = blockIdx.x * 4 + wid;
    if (row >= N3__) return;
    int w = row / 768, i = row - w * 768;
    const float* W = (w == 0) ? Wq : ((w == 1) ? Wk : Wv);
    const float* wr = W + (size_t)i * 768;
    double s = 0.0;
    #pragma unroll
    for (int j = 0; j < 12; j++) {
        float x = wr[lane + j * 64];
        s += fabs((double)x);
        sgnW[(size_t)row * 768 + lane + j * 64] =
            (signed char)((x > 0.f) - (x < 0.f));
    }
    #pragma unroll
    for (int off = 32; off; off >>= 1) s += __shfl_down(s, off);
    if (lane == 0) scales[row] = s * (1.0 / 768.0);
}

// ---------------------------------------------------------------------------
// Kernel 2: x -> fixed point (2^-28 quantum) -> 4 signed i8 digit planes.
// v = d0 + d1*2^8 + d2*2^16 + d3*2^24 exactly, each digit in [-128,127].
// ---------------------------------------------------------------------------
__global__ __launch_bounds__(256)
void prep_x_kernel(const float* __restrict__ hs, signed char* __restrict__ planes) {
    int idx = blockIdx.x * 256 + threadIdx.x;
    float x = hs[idx];
    double d = (double)x * 268435456.0;           // 2^28
    d = fmin(fmax(d, -2130706400.0), 2130706400.0);
    int v = __double2int_rn(d);
    int d0 = (int)(signed char)(v & 0xff);
    int r1 = (v - d0) >> 8;
    int d1 = (int)(signed char)(r1 & 0xff);
    int r2 = (r1 - d1) >> 8;
    int d2 = (int)(signed char)(r2 & 0xff);
    int r3 = (r2 - d2) >> 8;                      // in [-128,127] after clamp
    planes[idx]               = (signed char)d0;
    planes[PLANE__ + idx]     = (signed char)d1;
    planes[2 * PLANE__ + idx] = (signed char)d2;
    planes[3 * PLANE__ + idx] = (signed char)r3;
}

// ---------------------------------------------------------------------------
// Kernel 3: projection GEMM, exact. T[m,n] = sum_k x_fixed[m,k]*sign(W)[n,k]
// via 4 byte-plane i8 MFMAs, combined in int64, q = fp64(s*T*2^-28 + b).
// Writes q/k/v as bf16 [BH][S][HS], q/k sign bytes, v sign bytes transposed.
// Block 256 = 4 waves (2x2), wave tile 32x32, block tile 64x64.
// ---------------------------------------------------------------------------
__global__ __launch_bounds__(256)
void proj_kernel(const signed char* __restrict__ planes,
                 const signed char* __restrict__ sgnW,
                 const double* __restrict__ scales,
                 const float* __restrict__ bq, const float* __restrict__ bk,
                 const float* __restrict__ bv,
                 unsigned short* __restrict__ qkv,
                 signed char* __restrict__ qb, signed char* __restrict__ kb,
                 signed char* __restrict__ vbT) {
    int wid = threadIdx.x >> 6, lane = threadIdx.x & 63;
    int lrow = lane & 15, kgrp = lane >> 4;
    int m0 = blockIdx.x * 64 + (wid >> 1) * 32;
    int n0 = blockIdx.y * 64 + (wid & 1) * 32;

    int4v zero = {0, 0, 0, 0};
    int4v acc[2][2][4];
    #pragma unroll
    for (int mt = 0; mt < 2; mt++)
        #pragma unroll
        for (int nt = 0; nt < 2; nt++)
            #pragma unroll
            for (int p = 0; p < 4; p++) acc[mt][nt][p] = zero;

    for (int kc = 0; kc < 12; kc++) {
        int k = kc * 64 + kgrp * 16;
        int4v a[2][4], b[2];
        #pragma unroll
        for (int mt = 0; mt < 2; mt++)
            #pragma unroll
            for (int p = 0; p < 4; p++)
                a[mt][p] = *(const int4v*)(planes + (size_t)p * PLANE__ +
                                           (size_t)(m0 + mt * 16 + lrow) * 768 + k);
        #pragma unroll
        for (int nt = 0; nt < 2; nt++)
            b[nt] = *(const int4v*)(sgnW + (size_t)(n0 + nt * 16 + lrow) * 768 + k);
        #pragma unroll
        for (int mt = 0; mt < 2; mt++)
            #pragma unroll
            for (int nt = 0; nt < 2; nt++)
                #pragma unroll
                for (int p = 0; p < 4; p++)
                    acc[mt][nt][p] = __builtin_amdgcn_mfma_i32_16x16x64_i8(
                        a[mt][p], b[nt], acc[mt][nt][p], 0, 0, 0);
    }

    #pragma unroll
    for (int mt = 0; mt < 2; mt++) {
        #pragma unroll
        for (int nt = 0; nt < 2; nt++) {
            int ng = n0 + nt * 16 + lrow;
            int w = ng / 768;
            int i = ng - w * 768;
            int h = i >> 6, d = i & 63;
            double sc = scales[ng];
            float bias = (w == 0 ? bq : (w == 1 ? bk : bv))[i];
            #pragma unroll
            for (int r = 0; r < 4; r++) {
                long long comb = (long long)acc[mt][nt][0][r]
                               + ((long long)acc[mt][nt][1][r] << 8)
                               + ((long long)acc[mt][nt][2][r] << 16)
                               + ((long long)acc[mt][nt][3][r] << 24);
                int mg = m0 + mt * 16 + kgrp * 4 + r;
                double T = (double)comb * (1.0 / 268435456.0);
                double qv = fma(sc, T, (double)bias);
                int sg = (qv > 0.0) - (qv < 0.0);
                int b_ = mg >> 9, sidx = mg & 511;
                size_t oidx = (((size_t)b_ * NH__ + h) * S__ + sidx) * HS__ + d;
                qkv[(size_t)w * QKV_ELEMS__ + oidx] = f2bf((float)qv);
                if (w == 0)      qb[oidx] = (signed char)sg;
                else if (w == 1) kb[oidx] = (signed char)sg;
                else vbT[((size_t)(b_ * NH__ + h) * HS__ + d) * S__ + sidx] =
                         (signed char)sg;
            }
        }
    }
}

// ---------------------------------------------------------------------------
// Kernel 4: X @ X^T * 0.125 per (b,h) for q/k/v self-scores (bf16 MFMA).
// Block 256 = 4 waves, wave 32x32, block 64x64. grid (192, 8*8).
// ---------------------------------------------------------------------------
__global__ __launch_bounds__(256)
void score_kernel(const unsigned short* __restrict__ X, float* __restrict__ out) {
    int wid = threadIdx.x >> 6, lane = threadIdx.x & 63;
    int lrow = lane & 15, kgrp = lane >> 4;
    int bh = blockIdx.x;
    int mb = blockIdx.y >> 3, nb = blockIdx.y & 7;
    int m0 = mb * 64 + (wid >> 1) * 32;
    int n0 = nb * 64 + (wid & 1) * 32;
    const unsigned short* Xb = X + (size_t)bh * S__ * HS__;

    float4v acc[2][2];
    #pragma unroll
    for (int mt = 0; mt < 2; mt++)
        #pragma unroll
        for (int nt = 0; nt < 2; nt++) acc[mt][nt] = (float4v){0.f, 0.f, 0.f, 0.f};

    #pragma unroll
    for (int kc = 0; kc < 2; kc++) {
        int k = kc * 32 + kgrp * 8;
        short8 a[2], b[2];
        #pragma unroll
        for (int mt = 0; mt < 2; mt++)
            a[mt] = *(const short8*)(Xb + (size_t)(m0 + mt * 16 + lrow) * HS__ + k);
        #pragma unroll
        for (int nt = 0; nt < 2; nt++)
            b[nt] = *(const short8*)(Xb + (size_t)(n0 + nt * 16 + lrow) * HS__ + k);
        #pragma unroll
        for (int mt = 0; mt < 2; mt++)
            #pragma unroll
            for (int nt = 0; nt < 2; nt++)
                acc[mt][nt] = __builtin_amdgcn_mfma_f32_16x16x32_bf16(
                    a[mt], b[nt], acc[mt][nt], 0, 0, 0);
    }

    float* ob = out + (size_t)bh * S__ * S__;
    #pragma unroll
    for (int mt = 0; mt < 2; mt++)
        #pragma unroll
        for (int nt = 0; nt < 2; nt++)
            #pragma unroll
            for (int r = 0; r < 4; r++)
                ob[(size_t)(m0 + mt * 16 + kgrp * 4 + r) * S__ +
                   n0 + nt * 16 + lrow] = acc[mt][nt][r] * 0.125f;
}

// ---------------------------------------------------------------------------
// Kernel 5: attention scores (exact, i8 MFMA) + mask, probs in {0,1,2} (=2p)
// into LDS, then context = 0.5 * probs2 @ vb (exact, i8 MFMA over K=512).
// Block 256 = 4 waves; each wave owns 16 q-rows x all 512 cols (LDS private
// per wave -> no barrier). grid (192, 8).
// ---------------------------------------------------------------------------
__global__ __launch_bounds__(256)
void attn_kernel(const signed char* __restrict__ qb,
                 const signed char* __restrict__ kb,
                 const signed char* __restrict__ vbT,
                 const float* __restrict__ mask,
                 float* __restrict__ attn_out, float* __restrict__ ctx_out) {
    __shared__ signed char probs2[4][16][528];   // 528 = 512+16 pad (bank spread)
    int wid = threadIdx.x >> 6, lane = threadIdx.x & 63;
    int lrow = lane & 15, kgrp = lane >> 4;
    int bh = blockIdx.x;
    int b_ = bh / NH__, h = bh - b_ * NH__;
    int m0 = blockIdx.y * 64 + wid * 16;

    const signed char* qbb = qb + (size_t)bh * S__ * HS__;
    const signed char* kbb = kb + (size_t)bh * S__ * HS__;
    const float* mrow = mask + (size_t)b_ * S__;
    float* ao = attn_out + (size_t)bh * S__ * S__;

    int4v zero = {0, 0, 0, 0};
    int4v afrag = *(const int4v*)(qbb + (size_t)(m0 + lrow) * HS__ + kgrp * 16);

    for (int nt = 0; nt < 32; nt++) {
        int4v bfrag = *(const int4v*)(kbb + (size_t)(nt * 16 + lrow) * HS__ + kgrp * 16);
        int4v dacc = __builtin_amdgcn_mfma_i32_16x16x64_i8(afrag, bfrag, zero, 0, 0, 0);
        #pragma unroll
        for (int r = 0; r < 4; r++) {
            int rowl = kgrp * 4 + r;
            int col = nt * 16 + lrow;
            float sc = (float)dacc[r] * 0.125f + mrow[col];
            ao[(size_t)(m0 + rowl) * S__ + col] = sc;
            probs2[wid][rowl][col] =
                (signed char)(sc > 0.f ? 2 : (sc < 0.f ? 0 : 1));
        }
    }

    const signed char* vt = vbT + (size_t)bh * HS__ * S__;
    int4v acc2[4];
    #pragma unroll
    for (int dt = 0; dt < 4; dt++) acc2[dt] = zero;

    for (int kc = 0; kc < 8; kc++) {
        int k = kc * 64 + kgrp * 16;
        int4v a2 = *(const int4v*)(&probs2[wid][lrow][k]);
        #pragma unroll
        for (int dt = 0; dt < 4; dt++) {
            int4v b2 = *(const int4v*)(vt + (size_t)(dt * 16 + lrow) * S__ + k);
            acc2[dt] = __builtin_amdgcn_mfma_i32_16x16x64_i8(a2, b2, acc2[dt], 0, 0, 0);
        }
    }

    #pragma unroll
    for (int dt = 0; dt < 4; dt++)
        #pragma unroll
        for (int r = 0; r < 4; r++) {
            int srow = m0 + kgrp * 4 + r;
            int d = dt * 16 + lrow;
            ctx_out[((size_t)b_ * S__ + srow) * H__ + h * HS__ + d] =
                (float)acc2[dt][r] * 0.5f;
        }
}

// ---------------------------------------------------------------------------
extern "C" void kernel_launch(void* const* d_in, const int* in_sizes, int n_in,
                              void* d_out, int out_size, void* d_ws, size_t ws_size,
                              hipStream_t stream) {
    const float* hs   = (const float*)d_in[0];
    const float* mask = (const float*)d_in[1];
    const float* Wq   = (const float*)d_in[2];
    const float* bq   = (const float*)d_in[3];
    const float* Wk   = (const float*)d_in[4];
    const float* bk   = (const float*)d_in[5];
    const float* Wv   = (const float*)d_in[6];
    const float* bv   = (const float*)d_in[7];

    char* ws = (char*)d_ws;
    double*         scales = (double*)(ws);                    // 18432 B
    signed char*    sgnW   = (signed char*)(ws + 18432);       // 1769472 B
    signed char*    planes = (signed char*)(ws + 1787904);     // 25165824 B
    unsigned short* qkv    = (unsigned short*)(ws + 26953728); // 37748736 B
    signed char*    qb     = (signed char*)(ws + 64702464);    // 6291456 B
    signed char*    kb     = (signed char*)(ws + 70993920);    // 6291456 B
    signed char*    vbT    = (signed char*)(ws + 77285376);    // 6291456 B
    // total ws use: 83,576,832 bytes

    float* out  = (float*)d_out;
    float* ctx  = out;                    // [16,512,768]
    float* attn = out + 6291456;          // [16,12,512,512]
    float* vsc  = out + 56623104;         // value_scores
    float* qsc  = out + 106954752;        // query_scores
    float* ksc  = out + 157286400;        // key_scores

    hipLaunchKernelGGL(prep_w_kernel, dim3(576), dim3(256), 0, stream,
                       Wq, Wk, Wv, scales, sgnW);
    hipLaunchKernelGGL(prep_x_kernel, dim3(PLANE__ / 256), dim3(256), 0, stream,
                       hs, planes);
    hipLaunchKernelGGL(proj_kernel, dim3(128, 36), dim3(256), 0, stream,
                       planes, sgnW, scales, bq, bk, bv, qkv, qb, kb, vbT);
    hipLaunchKernelGGL(score_kernel, dim3(192, 64), dim3(256), 0, stream,
                       qkv, qsc);
    hipLaunchKernelGGL(score_kernel, dim3(192, 64), dim3(256), 0, stream,
                       qkv + (size_t)QKV_ELEMS__, ksc);
    hipLaunchKernelGGL(score_kernel, dim3(192, 64), dim3(256), 0, stream,
                       qkv + 2 * (size_t)QKV_ELEMS__, vsc);
    hipLaunchKernelGGL(attn_kernel, dim3(192, 8), dim3(256), 0, stream,
                       qb, kb, vbT, mask, attn, ctx);
}